// Round 2
// baseline (215.140 us; speedup 1.0000x reference)
//
#include <hip/hip_runtime.h>
#include <cmath>

#define NC 6
#define CF 64
#define HH 88
#define WW 160
#define NPIX 14080     // 88*160
#define NVOX 200000
#define VPRE 64

typedef unsigned int u32;

// ---------------- transpose [6][64][H*W] -> [6][H*W][64] (f32) ----------------
__global__ __launch_bounds__(256) void transpose_feats(const float* __restrict__ in,
                                                       float* __restrict__ out) {
    __shared__ float tile[64 * 65];
    int blk = blockIdx.x;            // 6 * 220
    int c = blk / 220;
    int p0 = (blk - c * 220) * 64;   // pixel tile base (14080/64 == 220 exact)
    int tid = threadIdx.x;
    int lane = tid & 63;
    int quad = tid >> 6;
    for (int r = quad; r < 64; r += 4)
        tile[r * 65 + lane] = in[(c * 64 + r) * NPIX + p0 + lane];   // coalesced read
    __syncthreads();
    for (int r = quad; r < 64; r += 4)
        out[((c * NPIX) + p0 + r) * 64 + lane] = tile[lane * 65 + r]; // coalesced write
}

// ---------------- main fused kernel: one block = 64 voxels ----------------
__global__ __launch_bounds__(256) void vox_main(
    const float* __restrict__ feats,   // [6][64][88][160] f32 (original)
    const float* __restrict__ featT,   // [6][88][160][64] f32 (transposed, in ws)
    const float* __restrict__ mask,    // [6][1][88][160]
    const float* __restrict__ Kg,      // [6][4][4]
    const float* __restrict__ ext,     // [6][4][4]
    const float* __restrict__ wno,     // [64][65]
    const float* __restrict__ bno,     // [64]
    const float* __restrict__ wo,      // [64][130]
    const float* __restrict__ bo,      // [64]
    float* __restrict__ outp,          // [64][200000] f32
    int useT)
{
    __shared__ __align__(16) float s_wno[64 * 68];    // row stride 68 (16B-aligned rows)
    __shared__ __align__(16) float s_wo[64 * 132];    // row stride 132 (16B-aligned rows)
    __shared__ float s_b[128];          // b_no | b_o
    __shared__ float s_ext[72];         // 6 cams x 12 (rows 0..2 of 4x4)
    __shared__ float s_K[54];           // 6 cams x 9 (3x3)
    __shared__ float4 s_pair[NC * 64];  // per (cam,voxel): x, y, depth, valid
    __shared__ __align__(16) float s_fbuf[4 * 132];   // per-wave feature vector
    __shared__ float s_stage[64 * 65];  // [out_row][voxel] staging (padded)

    int tid = threadIdx.x;
    int lane = tid & 63;
    int wv = tid >> 6;                // wave id 0..3
    int base = blockIdx.x * 64;       // first voxel of this block

    // ---- phase 0: preload weights / matrices into LDS ----
    for (int i = tid; i < 64 * 65; i += 256)
        s_wno[(i / 65) * 68 + (i % 65)] = wno[i];
    for (int i = tid; i < 64 * 130; i += 256)
        s_wo[(i / 130) * 132 + (i % 130)] = wo[i];
    if (tid < 64) s_b[tid] = bno[tid];
    else if (tid < 128) s_b[tid] = bo[tid - 64];
    if (tid < 72) s_ext[tid] = ext[(tid / 12) * 16 + (tid % 12)];
    if (tid >= 128 && tid < 182) {
        int i = tid - 128; int cam = i / 9; int e = i - cam * 9;
        s_K[i] = Kg[cam * 16 + (e / 3) * 4 + (e % 3)];
    }
    __syncthreads();

    // ---- phase 1: geometry, one lane per (cam, voxel) pair ----
    for (int p = tid; p < NC * 64; p += 256) {
        #pragma clang fp contract(off)   // match numpy's separate mul/add rounding
        int cam = p >> 6;
        int v = p & 63;
        int n = base + v;
        int xi = n % 100;
        int t = n / 100;
        int yi = t % 100;
        int zi = t / 100;
        float X = -50.0f + (float)xi;
        float Y = -50.0f + (float)yi;
        float Z = -15.0f + 1.5f * (float)zi;
        const float* E = s_ext + cam * 12;
        const float* Kk = s_K + cam * 9;
        float vl0 = E[0]*X + E[1]*Y + E[2]*Z + E[3];
        float vl1 = E[4]*X + E[5]*Y + E[6]*Z + E[7];
        float vl2 = E[8]*X + E[9]*Y + E[10]*Z + E[11];
        float c0 = Kk[0]*vl0 + Kk[1]*vl1 + Kk[2]*vl2;
        float c1 = Kk[3]*vl0 + Kk[4]*vl1 + Kk[5]*vl2;
        float c2 = Kk[6]*vl0 + Kk[7]*vl1 + Kk[8]*vl2;
        float pz = c2 + 1e-8f;
        float px = c0 / pz;
        float py = c1 / pz;
        float gx = (px / 159.0f - 0.5f) * 2.0f;
        float gy = (py / 87.0f - 0.5f) * 2.0f;
        float x = ((gx + 1.0f) * 0.5f) * 159.0f;   // exact reference roundtrip
        float y = ((gy + 1.0f) * 0.5f) * 87.0f;
        // nearest-mask sample (jnp.round == round-half-even == rintf)
        float xr = rintf(x), yr = rintf(y);
        bool nv = (xr >= 0.0f) && (xr <= 159.0f) && (yr >= 0.0f) && (yr <= 87.0f);
        float mval = 0.0f;
        if (nv) mval = mask[(cam * HH + (int)yr) * WW + (int)xr];
        bool ok = (mval > 0.5f) && (vl2 > 0.0f) &&
                  !((gx > 1.0f) || (gx < -1.0f) || (gy > 1.0f) || (gy < -1.0f));
        s_pair[cam * 64 + v] = make_float4(x, y, vl2, ok ? 1.0f : 0.0f);
    }
    __syncthreads();

    // ---- phase 2: per-voxel gather + matvec (one wave per voxel; no divergence) ----
    float* fb = s_fbuf + wv * 132;
    const float* fsrc = useT ? featT : feats;
    for (int it = 0; it < 16; ++it) {
        int v = wv * 16 + it;
        float4 pd[NC];
        int count = 0;
        #pragma unroll
        for (int c = 0; c < NC; ++c) {
            pd[c] = s_pair[c * 64 + v];               // broadcast reads
            count += (pd[c].w != 0.0f) ? 1 : 0;
        }
        float res = 0.0f;
        if (count == 1 || count == 2) {
            float f1 = 0.0f, f2 = 0.0f, d1 = 0.0f, d2 = 0.0f;
            #pragma unroll
            for (int c = 0; c < NC; ++c) {
                if (pd[c].w == 0.0f) continue;        // wave-uniform branch
                float x = pd[c].x, y = pd[c].y;
                float x0f = floorf(x), y0f = floorf(y);
                float wx1 = x - x0f, wx0 = 1.0f - wx1;
                float wy1 = y - y0f, wy0 = 1.0f - wy1;
                float xs[2] = {x0f, x0f + 1.0f};
                float ys[2] = {y0f, y0f + 1.0f};
                float wxs[2] = {wx0, wx1};
                float wys[2] = {wy0, wy1};
                float fv = 0.0f;
                #pragma unroll
                for (int a = 0; a < 2; ++a) {         // ref corner order: x outer, y inner
                    #pragma unroll
                    for (int b2 = 0; b2 < 2; ++b2) {
                        float xc = xs[a], yc = ys[b2];
                        float wgt = wxs[a] * wys[b2];
                        if (wgt != 0.0f && xc >= 0.0f && xc <= 159.0f &&
                            yc >= 0.0f && yc <= 87.0f) {
                            int pp = ((int)yc) * WW + (int)xc;
                            int idx = useT ? ((c * NPIX + pp) * 64 + lane)      // coalesced 256B
                                           : ((c * 64 + lane) * NPIX + pp);     // fallback
                            fv += wgt * fsrc[idx];
                        }
                    }
                }
                bool g2 = (c == 1) || (c == 2) || (c == 5);
                if (g2) { f2 += fv; d2 += pd[c].z / 100.0f; }
                else    { f1 += fv; d1 += pd[c].z / 100.0f; }
            }
            float acc;
            if (count == 1) {
                fb[lane] = f1 + f2;                   // exactly one group nonzero
                if (lane == 0) fb[64] = d1 + d2;
                asm volatile("s_waitcnt lgkmcnt(0)" ::: "memory"); // LDS in-order per wave
                acc = s_b[lane];
                const float* wr = s_wno + lane * 68;
                #pragma unroll
                for (int ch = 0; ch < 64; ch += 4) {
                    float4 f4 = *(const float4*)(fb + ch);        // broadcast b128
                    float4 w4 = *(const float4*)(wr + ch);        // 16B-aligned
                    acc += w4.x * f4.x;
                    acc += w4.y * f4.y;
                    acc += w4.z * f4.z;
                    acc += w4.w * f4.w;
                }
                acc += wr[64] * fb[64];
            } else {
                fb[lane] = f1;
                fb[65 + lane] = f2;
                if (lane == 0) { fb[64] = d1; fb[129] = d2; }
                asm volatile("s_waitcnt lgkmcnt(0)" ::: "memory");
                acc = s_b[64 + lane];
                const float* wr = s_wo + lane * 132;
                #pragma unroll
                for (int ch = 0; ch < 128; ch += 4) {
                    float4 f4 = *(const float4*)(fb + ch);
                    float4 w4 = *(const float4*)(wr + ch);
                    acc += w4.x * f4.x;
                    acc += w4.y * f4.y;
                    acc += w4.z * f4.z;
                    acc += w4.w * f4.w;
                }
                acc += wr[128] * fb[128];
                acc += wr[129] * fb[129];
            }
            res = acc > 0.0f ? acc : expm1f(acc);     // elu
        }
        s_stage[lane * 65 + v] = res;
    }
    __syncthreads();

    // ---- phase 3: coalesced f32 store, 256B per row-chunk ----
    for (int r = wv; r < 64; r += 4) {
        outp[(size_t)r * NVOX + base + lane] = s_stage[r * 65 + lane];
    }
}

extern "C" void kernel_launch(void* const* d_in, const int* in_sizes, int n_in,
                              void* d_out, int out_size, void* d_ws, size_t ws_size,
                              hipStream_t stream) {
    const float* feats = (const float*)d_in[0];
    const float* mask  = (const float*)d_in[1];
    const float* Kg    = (const float*)d_in[2];
    const float* ext   = (const float*)d_in[3];
    const float* wno   = (const float*)d_in[4];
    const float* bno   = (const float*)d_in[5];
    const float* wo    = (const float*)d_in[6];
    const float* bo    = (const float*)d_in[7];
    float* outp = (float*)d_out;
    float* featT = (float*)d_ws;

    size_t need = (size_t)NC * CF * NPIX * sizeof(float);   // 21.6 MB
    int useT = (ws_size >= need) ? 1 : 0;                   // constant across calls: graph-safe
    if (useT) {
        transpose_feats<<<NC * 220, 256, 0, stream>>>(feats, featT);
    }
    vox_main<<<NVOX / 64, 256, 0, stream>>>(feats, featT, mask, Kg, ext,
                                            wno, bno, wo, bo, outp, useT);
}

// Round 3
// 207.620 us; speedup vs baseline: 1.0362x; 1.0362x over previous
//
#include <hip/hip_runtime.h>
#include <cmath>

#define NC 6
#define CF 64
#define HH 88
#define WW 160
#define NPIX 14080     // 88*160
#define NVOX 200000
#define VPRE 64
#define VB 128         // voxels per block
#define NTH 1024       // threads per block (16 waves)

typedef unsigned int u32;

// ---------------- transpose [6][64][H*W] -> [6][H*W][64] (f32) ----------------
__global__ __launch_bounds__(256) void transpose_feats(const float* __restrict__ in,
                                                       float* __restrict__ out) {
    __shared__ float tile[64 * 65];
    int blk = blockIdx.x;            // 6 * 220
    int c = blk / 220;
    int p0 = (blk - c * 220) * 64;   // pixel tile base (14080/64 == 220 exact)
    int tid = threadIdx.x;
    int lane = tid & 63;
    int quad = tid >> 6;
    for (int r = quad; r < 64; r += 4)
        tile[r * 65 + lane] = in[(c * 64 + r) * NPIX + p0 + lane];   // coalesced read
    __syncthreads();
    for (int r = quad; r < 64; r += 4)
        out[((c * NPIX) + p0 + r) * 64 + lane] = tile[lane * 65 + r]; // coalesced write
}

// ---------------- main fused kernel: one block = 128 voxels, 16 waves ----------------
__global__ __launch_bounds__(NTH, 4) void vox_main(
    const float* __restrict__ feats,   // [6][64][88][160] f32 (original)
    const float* __restrict__ featT,   // [6][88][160][64] f32 (transposed, in ws)
    const float* __restrict__ mask,    // [6][1][88][160]
    const float* __restrict__ Kg,      // [6][4][4]
    const float* __restrict__ ext,     // [6][4][4]
    const float* __restrict__ wno,     // [64][65]
    const float* __restrict__ bno,     // [64]
    const float* __restrict__ wo,      // [64][130]
    const float* __restrict__ bo,      // [64]
    float* __restrict__ outp,          // [64][200000] f32
    int useT)
{
    __shared__ __align__(16) float s_wno[64 * 68];    // row stride 68 (16B-aligned; 17 granules -> b128-clean)
    __shared__ __align__(16) float s_wo[64 * 132];    // row stride 132 (33 granules -> b128-clean)
    __shared__ float s_b[128];          // b_no | b_o
    __shared__ float s_ext[72];         // 6 cams x 12
    __shared__ float s_K[54];           // 6 cams x 9
    __shared__ __align__(16) float4 s_pair[NC * VB];  // per (cam,voxel): x, y, depth, valid
    __shared__ __align__(16) float s_fbuf[16 * 132];  // per-wave feature vector
    __shared__ float s_stage[64 * 65];  // [out_row][64 voxels] staging (chunked reuse)

    int tid = threadIdx.x;
    int lane = tid & 63;
    int wv = tid >> 6;                // wave id 0..15
    int base = blockIdx.x * VB;       // first voxel of this block

    // ---- phase 0: preload weights / matrices into LDS ----
    for (int i = tid; i < 64 * 65; i += NTH)
        s_wno[(i / 65) * 68 + (i % 65)] = wno[i];
    for (int i = tid; i < 64 * 130; i += NTH)
        s_wo[(i / 130) * 132 + (i % 130)] = wo[i];
    if (tid < 64) s_b[tid] = bno[tid];
    else if (tid < 128) s_b[tid] = bo[tid - 64];
    if (tid >= 128 && tid < 200) {
        int i = tid - 128;
        s_ext[i] = ext[(i / 12) * 16 + (i % 12)];
    }
    if (tid >= 256 && tid < 310) {
        int i = tid - 256; int cam = i / 9; int e = i - cam * 9;
        s_K[i] = Kg[cam * 16 + (e / 3) * 4 + (e % 3)];
    }
    __syncthreads();

    // ---- phase 1: geometry, one lane per (cam, voxel) pair ----
    if (tid < NC * VB) {
        #pragma clang fp contract(off)   // match numpy's separate mul/add rounding
        int cam = tid >> 7;              // VB = 128
        int v = tid & (VB - 1);
        int n = base + v;
        if (n < NVOX) {
            int xi = n % 100;
            int t = n / 100;
            int yi = t % 100;
            int zi = t / 100;
            float X = -50.0f + (float)xi;
            float Y = -50.0f + (float)yi;
            float Z = -15.0f + 1.5f * (float)zi;
            const float* E = s_ext + cam * 12;
            const float* Kk = s_K + cam * 9;
            float vl0 = E[0]*X + E[1]*Y + E[2]*Z + E[3];
            float vl1 = E[4]*X + E[5]*Y + E[6]*Z + E[7];
            float vl2 = E[8]*X + E[9]*Y + E[10]*Z + E[11];
            float c0 = Kk[0]*vl0 + Kk[1]*vl1 + Kk[2]*vl2;
            float c1 = Kk[3]*vl0 + Kk[4]*vl1 + Kk[5]*vl2;
            float c2 = Kk[6]*vl0 + Kk[7]*vl1 + Kk[8]*vl2;
            float pz = c2 + 1e-8f;
            float px = c0 / pz;
            float py = c1 / pz;
            float gx = (px / 159.0f - 0.5f) * 2.0f;
            float gy = (py / 87.0f - 0.5f) * 2.0f;
            float x = ((gx + 1.0f) * 0.5f) * 159.0f;   // exact reference roundtrip
            float y = ((gy + 1.0f) * 0.5f) * 87.0f;
            // nearest-mask sample (jnp.round == round-half-even == rintf)
            float xr = rintf(x), yr = rintf(y);
            bool nv = (xr >= 0.0f) && (xr <= 159.0f) && (yr >= 0.0f) && (yr <= 87.0f);
            float mval = 0.0f;
            if (nv) mval = mask[(cam * HH + (int)yr) * WW + (int)xr];
            bool ok = (mval > 0.5f) && (vl2 > 0.0f) &&
                      !((gx > 1.0f) || (gx < -1.0f) || (gy > 1.0f) || (gy < -1.0f));
            s_pair[cam * VB + v] = make_float4(x, y, vl2, ok ? 1.0f : 0.0f);
        } else {
            s_pair[cam * VB + v] = make_float4(0.0f, 0.0f, 0.0f, 0.0f);
        }
    }
    __syncthreads();

    // ---- phase 2: per-voxel gather + matvec (one wave per voxel; 8 voxels/wave) ----
    float* fb = s_fbuf + wv * 132;
    const float* fsrc = useT ? featT : feats;
    const float* pw = (const float*)s_pair;
    float rr[8];
    for (int it = 0; it < 8; ++it) {
        int v = wv * 8 + it;
        // count valid cams (scalar .w reads only; wave-uniform)
        int cnt = 0, cam0 = 0, cam1 = 0;
        #pragma unroll
        for (int c = 0; c < NC; ++c) {
            float w = pw[(c * VB + v) * 4 + 3];
            if (w != 0.0f) { if (cnt == 0) cam0 = c; else cam1 = c; ++cnt; }
        }
        float res = 0.0f;
        if (cnt == 1 || cnt == 2) {
            float f1 = 0.0f, f2 = 0.0f, d1 = 0.0f, d2 = 0.0f;
            for (int j = 0; j < cnt; ++j) {
                int c = j ? cam1 : cam0;
                float4 pd = s_pair[c * VB + v];
                float x = pd.x, y = pd.y;
                float x0f = floorf(x), y0f = floorf(y);
                float wx1 = x - x0f, wx0 = 1.0f - wx1;
                float wy1 = y - y0f, wy0 = 1.0f - wy1;
                float x1f = x0f + 1.0f, y1f = y0f + 1.0f;
                float bx0 = (x0f >= 0.0f && x0f <= 159.0f) ? 1.0f : 0.0f;
                float bx1 = (x1f >= 0.0f && x1f <= 159.0f) ? 1.0f : 0.0f;
                float by0 = (y0f >= 0.0f && y0f <= 87.0f) ? 1.0f : 0.0f;
                float by1 = (y1f >= 0.0f && y1f <= 87.0f) ? 1.0f : 0.0f;
                int ix0 = (int)fminf(fmaxf(x0f, 0.0f), 159.0f);
                int ix1 = (int)fminf(fmaxf(x1f, 0.0f), 159.0f);
                int iy0 = (int)fminf(fmaxf(y0f, 0.0f), 87.0f);
                int iy1 = (int)fminf(fmaxf(y1f, 0.0f), 87.0f);
                // idx = pix*A + Boff  (uniform A per layout)
                int A = useT ? 64 : 1;
                int Boff = useT ? (c * NPIX * 64 + lane) : ((c * 64 + lane) * NPIX);
                int p00 = (iy0 * WW + ix0) * A + Boff;
                int p01 = (iy1 * WW + ix0) * A + Boff;
                int p10 = (iy0 * WW + ix1) * A + Boff;
                int p11 = (iy1 * WW + ix1) * A + Boff;
                float v00 = fsrc[p00];               // 4 independent loads in flight
                float v01 = fsrc[p01];
                float v10 = fsrc[p10];
                float v11 = fsrc[p11];
                float fv;                             // reference corner order: x outer, y inner
                fv  = (wx0 * wy0 * bx0 * by0) * v00;
                fv += (wx0 * wy1 * bx0 * by1) * v01;
                fv += (wx1 * wy0 * bx1 * by0) * v10;
                fv += (wx1 * wy1 * bx1 * by1) * v11;
                float d = pd.z / 100.0f;
                if (c == 1 || c == 2 || c == 5) { f2 += fv; d2 += d; }
                else                            { f1 += fv; d1 += d; }
            }
            float a0, a1 = 0.0f, a2 = 0.0f, a3 = 0.0f;
            if (cnt == 1) {
                fb[lane] = f1 + f2;                   // exactly one group nonzero
                if (lane == 0) fb[64] = d1 + d2;
                asm volatile("s_waitcnt lgkmcnt(0)" ::: "memory");
                a0 = s_b[lane];
                const float* wr = s_wno + lane * 68;
                #pragma unroll
                for (int ch = 0; ch < 64; ch += 16) { // 4 independent acc chains
                    float4 fA = *(const float4*)(fb + ch);
                    float4 wA = *(const float4*)(wr + ch);
                    float4 fB = *(const float4*)(fb + ch + 4);
                    float4 wB = *(const float4*)(wr + ch + 4);
                    float4 fC = *(const float4*)(fb + ch + 8);
                    float4 wC = *(const float4*)(wr + ch + 8);
                    float4 fD = *(const float4*)(fb + ch + 12);
                    float4 wD = *(const float4*)(wr + ch + 12);
                    a0 += wA.x*fA.x; a0 += wA.y*fA.y; a0 += wA.z*fA.z; a0 += wA.w*fA.w;
                    a1 += wB.x*fB.x; a1 += wB.y*fB.y; a1 += wB.z*fB.z; a1 += wB.w*fB.w;
                    a2 += wC.x*fC.x; a2 += wC.y*fC.y; a2 += wC.z*fC.z; a2 += wC.w*fC.w;
                    a3 += wD.x*fD.x; a3 += wD.y*fD.y; a3 += wD.z*fD.z; a3 += wD.w*fD.w;
                }
                a0 += wr[64] * fb[64];
            } else {
                fb[lane] = f1;
                fb[65 + lane] = f2;
                if (lane == 0) { fb[64] = d1; fb[129] = d2; }
                asm volatile("s_waitcnt lgkmcnt(0)" ::: "memory");
                a0 = s_b[64 + lane];
                const float* wr = s_wo + lane * 132;
                #pragma unroll
                for (int ch = 0; ch < 128; ch += 16) {
                    float4 fA = *(const float4*)(fb + ch);
                    float4 wA = *(const float4*)(wr + ch);
                    float4 fB = *(const float4*)(fb + ch + 4);
                    float4 wB = *(const float4*)(wr + ch + 4);
                    float4 fC = *(const float4*)(fb + ch + 8);
                    float4 wC = *(const float4*)(wr + ch + 8);
                    float4 fD = *(const float4*)(fb + ch + 12);
                    float4 wD = *(const float4*)(wr + ch + 12);
                    a0 += wA.x*fA.x; a0 += wA.y*fA.y; a0 += wA.z*fA.z; a0 += wA.w*fA.w;
                    a1 += wB.x*fB.x; a1 += wB.y*fB.y; a1 += wB.z*fB.z; a1 += wB.w*fB.w;
                    a2 += wC.x*fC.x; a2 += wC.y*fC.y; a2 += wC.z*fC.z; a2 += wC.w*fC.w;
                    a3 += wD.x*fD.x; a3 += wD.y*fD.y; a3 += wD.z*fD.z; a3 += wD.w*fD.w;
                }
                a0 += wr[128] * fb[128];
                a1 += wr[129] * fb[129];
            }
            float acc = (a0 + a1) + (a2 + a3);
            res = acc > 0.0f ? acc : expm1f(acc);     // elu
        }
        rr[it] = res;
    }

    // ---- phase 3: chunked stage + coalesced store (2 chunks of 64 voxels) ----
    for (int j = 0; j < 2; ++j) {
        __syncthreads();
        if ((wv >> 3) == j) {                        // owning 8 waves write their 64 voxels
            int colbase = (wv & 7) * 8;
            #pragma unroll
            for (int it = 0; it < 8; ++it)
                s_stage[lane * 65 + colbase + it] = rr[it];
        }
        __syncthreads();
        int cb = base + j * 64;
        if (cb + lane < NVOX) {
            #pragma unroll
            for (int r4 = 0; r4 < 4; ++r4) {
                int r = wv * 4 + r4;
                outp[(size_t)r * NVOX + cb + lane] = s_stage[r * 65 + lane];
            }
        }
    }
}

extern "C" void kernel_launch(void* const* d_in, const int* in_sizes, int n_in,
                              void* d_out, int out_size, void* d_ws, size_t ws_size,
                              hipStream_t stream) {
    const float* feats = (const float*)d_in[0];
    const float* mask  = (const float*)d_in[1];
    const float* Kg    = (const float*)d_in[2];
    const float* ext   = (const float*)d_in[3];
    const float* wno   = (const float*)d_in[4];
    const float* bno   = (const float*)d_in[5];
    const float* wo    = (const float*)d_in[6];
    const float* bo    = (const float*)d_in[7];
    float* outp = (float*)d_out;
    float* featT = (float*)d_ws;

    size_t need = (size_t)NC * CF * NPIX * sizeof(float);   // 21.6 MB
    int useT = (ws_size >= need) ? 1 : 0;                   // constant across calls: graph-safe
    if (useT) {
        transpose_feats<<<NC * 220, 256, 0, stream>>>(feats, featT);
    }
    int nblk = (NVOX + VB - 1) / VB;                        // 1563
    vox_main<<<nblk, NTH, 0, stream>>>(feats, featT, mask, Kg, ext,
                                       wno, bno, wo, bo, outp, useT);
}